// Round 16
// baseline (235.285 us; speedup 1.0000x reference)
//
#include <hip/hip_runtime.h>
#include <hip/hip_bf16.h>
#include <hip/hip_fp16.h>
#include <math.h>

#define NN 20000
#define NE 320000
#define SLOT 64  // padded-CSR slots per node; P(deg>64) ~ 1e-18 at mean 16

typedef __attribute__((ext_vector_type(8))) _Float16 f16x8;
typedef __attribute__((ext_vector_type(2))) _Float16 h16x2;
typedef __attribute__((ext_vector_type(4))) float f32x4;

__device__ inline ushort f2h(float f) {
    __half h = __float2half_rn(f);
    return *reinterpret_cast<ushort*>(&h);
}
__device__ inline uint pack2h(float a, float b) {
    return (uint)f2h(a) | ((uint)f2h(b) << 16);
}
__device__ inline h16x2 u2h2(uint x) {
    union { uint u; h16x2 h; } c; c.u = x; return c.h;
}
__device__ inline float2 uh2f2(uint u) {
    union { uint i; __half2 h; } c; c.i = u;
    return __half22float2(c.h);
}
// v_perm_b32: sel idx 0-3 -> bytes of 2nd arg, 4-7 -> bytes of 1st arg
__device__ inline uint pack_lo(uint x, uint y) {  // (lo16(x), lo16(y))
    return __builtin_amdgcn_perm(x, y, 0x01000504u);
}
__device__ inline uint pack_hi(uint x, uint y) {  // (hi16(x), hi16(y))
    return __builtin_amdgcn_perm(x, y, 0x03020706u);
}

__device__ inline float fast_tanh(float x) {
    x = fminf(fmaxf(x, -9.f), 9.f);
    float e = __expf(2.f * x);
    return 1.f - 2.f / (e + 1.f);
}

struct EdgeParams {
    const float *pw0, *pb0, *mu0, *is0;
    const float *pw1, *pb1, *mu1, *is1;
    const float *pw2, *pb2, *mu2, *is2;
};

__device__ inline void layer_w(float p0, float p1, const float* pw, const float* pb,
                               const float* mu, const float* is, float* out4) {
    float u0 = fast_tanh(p0 * pw[0] + p1 * pw[2] + pb[0]);
    float u1 = fast_tanh(p0 * pw[1] + p1 * pw[3] + pb[1]);
#pragma unroll
    for (int k = 0; k < 4; ++k) {
        float d0 = (u0 - mu[k * 2 + 0]) * is[k * 2 + 0];
        float d1 = (u1 - mu[k * 2 + 1]) * is[k * 2 + 1];
        out4[k] = __expf(-0.5f * (d0 * d0 + d1 * d1));
    }
}

// ---- k_scatter: slim 8B scatter (blocks 0..1249) + LDS-tile weight transpose
//      (1250..1289) + features->f16 (1290..1914) ----
__global__ void k_scatter(const int* __restrict__ dst, const int* __restrict__ src,
                          const float* __restrict__ pseudo,
                          int* __restrict__ cursor, uint2* __restrict__ sp,
                          const float* __restrict__ features, ushort* __restrict__ fbf,
                          const float* __restrict__ f0, const float* __restrict__ f1,
                          const float* __restrict__ f2, ushort* __restrict__ w0,
                          ushort* __restrict__ w1, ushort* __restrict__ w2) {
    __shared__ float tile[64][65];
    int bid = blockIdx.x;
    if (bid < 1250) {
        int e = bid * 256 + threadIdx.x;  // 1250*256 == NE exactly
        int n = dst[e];
        int pos = atomicAdd(&cursor[n], 1);
        if (pos < SLOT) {
            float2 p = *(const float2*)(pseudo + (size_t)e * 2);  // contiguous read
            sp[(size_t)n * SLOT + pos] = make_uint2((uint)src[e], pack2h(p.x, p.y));
        }
    } else if (bid < 1290) {
        // LDS-tile transpose: w[n][k*din+d] = fc_w[d][k*128+n], 64x64 tiles, both coalesced
        int b = bid - 1250;  // 0..39
        const float* srcp;
        ushort* dstp;
        int din, KD, k, nt, dt;
        if (b < 8)       { srcp = f0; dstp = w0; din = 64;  KD = 256; k = b >> 1; nt = b & 1; dt = 0; }
        else if (b < 24) { int t = b - 8;  srcp = f1; dstp = w1; din = 128; KD = 512; k = t >> 2; nt = (t >> 1) & 1; dt = t & 1; }
        else             { int t = b - 24; srcp = f2; dstp = w2; din = 128; KD = 512; k = t >> 2; nt = (t >> 1) & 1; dt = t & 1; }
        int n0 = nt * 64, d0 = dt * 64;
        int tx = threadIdx.x & 63, ty = threadIdx.x >> 6;  // 64 x 4
#pragma unroll
        for (int ii = 0; ii < 16; ++ii) {
            int dr = ty * 16 + ii;
            tile[dr][tx] = srcp[(size_t)(d0 + dr) * 512 + k * 128 + n0 + tx];
        }
        __syncthreads();
#pragma unroll
        for (int ii = 0; ii < 16; ++ii) {
            int nr = ty * 16 + ii;
            dstp[(size_t)(n0 + nr) * KD + k * din + d0 + tx] = f2h(tile[tx][nr]);
        }
    } else {
        // features f32 -> f16: 20000*64 = 1.28M elems, 8 per thread, 625 blocks exact
        int idx = (bid - 1290) * 256 + threadIdx.x;  // < 160000
        size_t b8 = (size_t)idx * 8;
        float4 a = *(const float4*)(features + b8);
        float4 b = *(const float4*)(features + b8 + 4);
        uint4 o;
        o.x = pack2h(a.x, a.y);
        o.y = pack2h(a.z, a.w);
        o.z = pack2h(b.x, b.y);
        o.w = pack2h(b.z, b.w);
        *(uint4*)(fbf + b8) = o;
    }
}

// ---- k_wcompute: dense per-slot mixture weights for all 3 layers (coalesced) ----
// Reads sp[slot].y (f16x2 pseudo), writes cw0/cw1/cw2[slot] as packed half4 (uint2).
// Unfilled slots compute garbage (possibly NaN) weights that layers never use
// (weight registers are zeroed by the deg-predicate before the dot product).
__global__ void k_wcompute(const uint2* __restrict__ sp, EdgeParams P,
                           uint2* __restrict__ cw0, uint2* __restrict__ cw1,
                           uint2* __restrict__ cw2) {
    int slot = blockIdx.x * 256 + threadIdx.x;  // grid 5000 -> 1.28M exact
    float2 p = uh2f2(sp[slot].y);
    float w[4];
    layer_w(p.x, p.y, P.pw0, P.pb0, P.mu0, P.is0, w);
    cw0[slot] = make_uint2(pack2h(w[0], w[1]), pack2h(w[2], w[3]));
    layer_w(p.x, p.y, P.pw1, P.pb1, P.mu1, P.is1, w);
    cw1[slot] = make_uint2(pack2h(w[0], w[1]), pack2h(w[2], w[3]));
    layer_w(p.x, p.y, P.pw2, P.pb2, P.mu2, P.is2, w);
    cw2[slot] = make_uint2(pack2h(w[0], w[1]), pack2h(w[2], w[3]));
}

// ------ fused layer: R15 agg (fdot2) with dense per-layer metadata + K-SPLIT f16 GEMM ------
template <int DIN, bool OUTF16>
__global__ __launch_bounds__(1024, 8) void layer_fused(
    const ushort* __restrict__ hbf, const int* __restrict__ cursor,
    const uint2* __restrict__ sp, const uint2* __restrict__ cw,
    const ushort* __restrict__ Bt, const float* __restrict__ bias,
    void* __restrict__ hout) {
    constexpr int KD = 4 * DIN;
    constexpr int PITCH = KD + 8;   // ushorts; 16B-aligned rows
    constexpr int B = 8;            // batch slots; 16 edges (2 per slot via halves)
    constexpr int FPL = DIN / 32;   // features per lane (2 or 4)
    __shared__ __align__(16) ushort Ts[16 * PITCH];
    __shared__ __align__(16) f32x4 red[8][64];  // K-split partials (8 KB)
    int wv = threadIdx.x >> 6, lane = threadIdx.x & 63;
    int l16 = lane & 15, quad = lane >> 4;
    int half = lane >> 5, l32 = lane & 31;
    int nb = blockIdx.x * 16;
    int n = nb + wv;

    // ---- aggregation: one node per wave, fdot2 accumulate ----
    {
        int deg = __builtin_amdgcn_readfirstlane(cursor[n]);
        deg = deg < SLOT ? deg : SLOT;  // safety clamp
        size_t base = (size_t)n * SLOT;

        float acc[4 * FPL];
#pragma unroll
        for (int j = 0; j < 4 * FPL; ++j) acc[j] = 0.f;

        for (int i = 0; i < deg; i += 2 * B) {
            int s[B];
            uint wlo[B], whi[B];
            uint2 hv[B];  // DIN==64 uses only .x
#pragma unroll
            for (int u = 0; u < B; ++u) {
                int ii = i + 2 * u + half;  // uniform within each half-wave
                bool ok = ii < deg;
                size_t idx = base + (ok ? ii : 0);
                s[u] = (int)sp[idx].x;
                uint2 wp = cw[idx];
                wlo[u] = ok ? wp.x : 0u;
                whi[u] = ok ? wp.y : 0u;
            }
#pragma unroll
            for (int u = 0; u < B; ++u) {
                const ushort* rowp = hbf + (size_t)s[u] * DIN + l32 * FPL;
                if (DIN == 64)
                    hv[u].x = *(const uint*)rowp;
                else
                    hv[u] = *(const uint2*)rowp;
            }
#pragma unroll
            for (int u = 0; u < B; u += 2) {
                // weight pairs (edge u, edge u+1) per mixture-k
                uint wp0 = pack_lo(wlo[u], wlo[u + 1]);
                uint wp1 = pack_hi(wlo[u], wlo[u + 1]);
                uint wp2 = pack_lo(whi[u], whi[u + 1]);
                uint wp3 = pack_hi(whi[u], whi[u + 1]);
                h16x2 w2[4] = {u2h2(wp0), u2h2(wp1), u2h2(wp2), u2h2(wp3)};
                h16x2 f2[FPL];
                f2[0] = u2h2(pack_lo(hv[u].x, hv[u + 1].x));
                f2[1] = u2h2(pack_hi(hv[u].x, hv[u + 1].x));
                if (DIN == 128) {
                    f2[2] = u2h2(pack_lo(hv[u].y, hv[u + 1].y));
                    f2[3] = u2h2(pack_hi(hv[u].y, hv[u + 1].y));
                }
#pragma unroll
                for (int k = 0; k < 4; ++k)
#pragma unroll
                    for (int j = 0; j < FPL; ++j)
                        acc[k * FPL + j] = __builtin_amdgcn_fdot2(
                            w2[k], f2[j], acc[k * FPL + j], false);
            }
        }
        // cross-half combine
#pragma unroll
        for (int j = 0; j < 4 * FPL; ++j) acc[j] += __shfl_xor(acc[j], 32);

        if (half == 0) {
#pragma unroll
            for (int k = 0; k < 4; ++k) {
                if (DIN == 64) {
                    ushort2 p;
                    p.x = f2h(acc[k * 2 + 0]);
                    p.y = f2h(acc[k * 2 + 1]);
                    *(ushort2*)(Ts + wv * PITCH + k * DIN + l32 * 2) = p;
                } else {
                    ushort4 p;
                    p.x = f2h(acc[k * 4 + 0]);
                    p.y = f2h(acc[k * 4 + 1]);
                    p.z = f2h(acc[k * 4 + 2]);
                    p.w = f2h(acc[k * 4 + 3]);
                    *(ushort4*)(Ts + wv * PITCH + k * DIN + l32 * 4) = p;
                }
            }
        }
    }
    __syncthreads();

    // ---- GEMM phase: 16 waves, K-split, f16 MFMA ----
    {
        constexpr int KH = KD / 2;
        int kh = wv >> 3;
        int ct = wv & 7;
        int c0 = ct * 16;
        f32x4 accg = (f32x4){0.f, 0.f, 0.f, 0.f};
        int kbeg = kh * KH;
#pragma unroll 4
        for (int k0 = kbeg; k0 < kbeg + KH; k0 += 32) {
            f16x8 af = *(const f16x8*)(Ts + l16 * PITCH + k0 + quad * 8);
            f16x8 bfr = *(const f16x8*)(Bt + (size_t)(c0 + l16) * KD + k0 + quad * 8);
            accg = __builtin_amdgcn_mfma_f32_16x16x32_f16(af, bfr, accg, 0, 0, 0);
        }
        if (kh == 1) red[ct][lane] = accg;
        __syncthreads();
        if (kh == 0) {
            f32x4 other = red[ct][lane];
            int gn = c0 + l16;
            float bv = bias[gn];
#pragma unroll
            for (int i = 0; i < 4; ++i) {
                int gm = nb + quad * 4 + i;
                float val = accg[i] + other[i] + bv;
                if (OUTF16)
                    ((ushort*)hout)[(size_t)gm * 128 + gn] = f2h(val);
                else
                    ((float*)hout)[(size_t)gm * 128 + gn] = val;
            }
        }
    }
}

extern "C" void kernel_launch(void* const* d_in, const int* in_sizes, int n_in,
                              void* d_out, int out_size, void* d_ws, size_t ws_size,
                              hipStream_t stream) {
    const float* features = (const float*)d_in[0];
    const float* pseudo = (const float*)d_in[1];
    const int* src = (const int*)d_in[2];
    const int* dst = (const int*)d_in[3];
    const float* fc_w[3] = {(const float*)d_in[4], (const float*)d_in[10], (const float*)d_in[16]};
    const float* mu[3] = {(const float*)d_in[5], (const float*)d_in[11], (const float*)d_in[17]};
    const float* isg[3] = {(const float*)d_in[6], (const float*)d_in[12], (const float*)d_in[18]};
    const float* bias[3] = {(const float*)d_in[7], (const float*)d_in[13], (const float*)d_in[19]};
    const float* pw[3] = {(const float*)d_in[8], (const float*)d_in[14], (const float*)d_in[20]};
    const float* pb[3] = {(const float*)d_in[9], (const float*)d_in[15], (const float*)d_in[21]};

    char* ws = (char*)d_ws;
    auto alloc = [&](size_t bytes) -> void* {
        void* p = (void*)ws;
        ws += (bytes + 255) & ~(size_t)255;
        return p;
    };
    int* cursor = (int*)alloc((size_t)NN * 4);
    uint2* sp = (uint2*)alloc((size_t)NN * SLOT * 8);     // {src, pseudo f16x2}
    uint2* cw0 = (uint2*)alloc((size_t)NN * SLOT * 8);    // half4 weights / slot
    uint2* cw1 = (uint2*)alloc((size_t)NN * SLOT * 8);
    uint2* cw2 = (uint2*)alloc((size_t)NN * SLOT * 8);
    ushort* fbf = (ushort*)alloc((size_t)NN * 64 * 2);    // features in f16
    ushort* w2t_0 = (ushort*)alloc((size_t)128 * 256 * 2);
    ushort* w2t_1 = (ushort*)alloc((size_t)128 * 512 * 2);
    ushort* w2t_2 = (ushort*)alloc((size_t)128 * 512 * 2);
    ushort* h1 = (ushort*)alloc((size_t)NN * 128 * 2);
    ushort* h2 = (ushort*)alloc((size_t)NN * 128 * 2);

    hipMemsetAsync(cursor, 0, (size_t)NN * 4, stream);
    EdgeParams P;
    P.pw0 = pw[0]; P.pb0 = pb[0]; P.mu0 = mu[0]; P.is0 = isg[0];
    P.pw1 = pw[1]; P.pb1 = pb[1]; P.mu1 = mu[1]; P.is1 = isg[1];
    P.pw2 = pw[2]; P.pb2 = pb[2]; P.mu2 = mu[2]; P.is2 = isg[2];

    k_scatter<<<1915, 256, 0, stream>>>(dst, src, pseudo, cursor, sp, features, fbf,
                                        fc_w[0], fc_w[1], fc_w[2], w2t_0, w2t_1, w2t_2);
    k_wcompute<<<5000, 256, 0, stream>>>(sp, P, cw0, cw1, cw2);

    const int GB = NN / 16;  // 1250 blocks, 16 waves each, 1 node/wave

    layer_fused<64, true><<<GB, 1024, 0, stream>>>(
        fbf, cursor, sp, cw0, w2t_0, bias[0], h1);
    layer_fused<128, true><<<GB, 1024, 0, stream>>>(
        h1, cursor, sp, cw1, w2t_1, bias[1], h2);
    layer_fused<128, false><<<GB, 1024, 0, stream>>>(
        h2, cursor, sp, cw2, w2t_2, bias[2], (float*)d_out);
}

// Round 17
// 223.042 us; speedup vs baseline: 1.0549x; 1.0549x over previous
//
#include <hip/hip_runtime.h>
#include <hip/hip_bf16.h>
#include <hip/hip_fp16.h>
#include <math.h>

#define NN 20000
#define NE 320000
#define SLOT 64  // padded-CSR slots per node; P(deg>64) ~ 1e-18 at mean 16

typedef __attribute__((ext_vector_type(8))) _Float16 f16x8;
typedef __attribute__((ext_vector_type(2))) _Float16 h16x2;
typedef __attribute__((ext_vector_type(4))) float f32x4;

__device__ inline ushort f2h(float f) {
    __half h = __float2half_rn(f);
    return *reinterpret_cast<ushort*>(&h);
}
__device__ inline uint pack2h(float a, float b) {
    return (uint)f2h(a) | ((uint)f2h(b) << 16);
}
__device__ inline h16x2 u2h2(uint x) {
    union { uint u; h16x2 h; } c; c.u = x; return c.h;
}
// v_perm_b32: sel idx 0-3 -> bytes of 2nd arg, 4-7 -> bytes of 1st arg
__device__ inline uint pack_lo(uint x, uint y) {  // (lo16(x), lo16(y))
    return __builtin_amdgcn_perm(x, y, 0x01000504u);
}
__device__ inline uint pack_hi(uint x, uint y) {  // (hi16(x), hi16(y))
    return __builtin_amdgcn_perm(x, y, 0x03020706u);
}

__device__ inline float fast_tanh(float x) {
    x = fminf(fmaxf(x, -9.f), 9.f);
    float e = __expf(2.f * x);
    return 1.f - 2.f / (e + 1.f);
}

struct EdgeParams {
    const float *pw0, *pb0, *mu0, *is0;
    const float *pw1, *pb1, *mu1, *is1;
    const float *pw2, *pb2, *mu2, *is2;
};

__device__ inline void layer_w(float p0, float p1, const float* pw, const float* pb,
                               const float* mu, const float* is, float* out4) {
    float u0 = fast_tanh(p0 * pw[0] + p1 * pw[2] + pb[0]);
    float u1 = fast_tanh(p0 * pw[1] + p1 * pw[3] + pb[1]);
#pragma unroll
    for (int k = 0; k < 4; ++k) {
        float d0 = (u0 - mu[k * 2 + 0]) * is[k * 2 + 0];
        float d1 = (u1 - mu[k * 2 + 1]) * is[k * 2 + 1];
        out4[k] = __expf(-0.5f * (d0 * d0 + d1 * d1));
    }
}

// ---- prep: edge records (blocks 0..1249) + LDS-tile weight transpose (1250..1289)
//      + features->f16 (1290..1914). All activations/weights stored f16. ----
__global__ void fill_prep(const int* __restrict__ dst, const int* __restrict__ src,
                          const float* __restrict__ pseudo, EdgeParams P,
                          int* __restrict__ cursor, uint* __restrict__ recs,
                          const float* __restrict__ features, ushort* __restrict__ fbf,
                          const float* __restrict__ f0, const float* __restrict__ f1,
                          const float* __restrict__ f2, ushort* __restrict__ w0,
                          ushort* __restrict__ w1, ushort* __restrict__ w2) {
    __shared__ float tile[64][65];
    int bid = blockIdx.x;
    if (bid < 1250) {
        int e = bid * 256 + threadIdx.x;  // 1250*256 == NE exactly
        int n = dst[e];
        int pos = atomicAdd(&cursor[n], 1);
        if (pos < SLOT) {
            size_t slot = (size_t)n * SLOT + pos;
            float2 p = *(const float2*)(pseudo + (size_t)e * 2);  // contiguous read
            float w[4];
            uint pk0x, pk0y, pk1x, pk1y, pk2x, pk2y;
            layer_w(p.x, p.y, P.pw0, P.pb0, P.mu0, P.is0, w);
            pk0x = pack2h(w[0], w[1]);
            pk0y = pack2h(w[2], w[3]);
            layer_w(p.x, p.y, P.pw1, P.pb1, P.mu1, P.is1, w);
            pk1x = pack2h(w[0], w[1]);
            pk1y = pack2h(w[2], w[3]);
            layer_w(p.x, p.y, P.pw2, P.pb2, P.mu2, P.is2, w);
            pk2x = pack2h(w[0], w[1]);
            pk2y = pack2h(w[2], w[3]);
            uint* r = recs + slot * 8;
            *(uint4*)(r + 0) = make_uint4((uint)src[e], 0u, pk0x, pk0y);
            *(uint4*)(r + 4) = make_uint4(pk1x, pk1y, pk2x, pk2y);
        }
    } else if (bid < 1290) {
        // LDS-tile transpose: w[n][k*din+d] = fc_w[d][k*128+n], 64x64 tiles, both coalesced
        int b = bid - 1250;  // 0..39
        const float* srcp;
        ushort* dstp;
        int din, KD, k, nt, dt;
        if (b < 8)       { srcp = f0; dstp = w0; din = 64;  KD = 256; k = b >> 1; nt = b & 1; dt = 0; }
        else if (b < 24) { int t = b - 8;  srcp = f1; dstp = w1; din = 128; KD = 512; k = t >> 2; nt = (t >> 1) & 1; dt = t & 1; }
        else             { int t = b - 24; srcp = f2; dstp = w2; din = 128; KD = 512; k = t >> 2; nt = (t >> 1) & 1; dt = t & 1; }
        int n0 = nt * 64, d0 = dt * 64;
        int tx = threadIdx.x & 63, ty = threadIdx.x >> 6;  // 64 x 4
#pragma unroll
        for (int ii = 0; ii < 16; ++ii) {
            int dr = ty * 16 + ii;
            tile[dr][tx] = srcp[(size_t)(d0 + dr) * 512 + k * 128 + n0 + tx];
        }
        __syncthreads();
#pragma unroll
        for (int ii = 0; ii < 16; ++ii) {
            int nr = ty * 16 + ii;
            dstp[(size_t)(n0 + nr) * KD + k * din + d0 + tx] = f2h(tile[tx][nr]);
        }
    } else {
        // features f32 -> f16: 20000*64 = 1.28M elems, 8 per thread, 625 blocks exact
        int idx = (bid - 1290) * 256 + threadIdx.x;  // < 160000
        size_t b8 = (size_t)idx * 8;
        float4 a = *(const float4*)(features + b8);
        float4 b = *(const float4*)(features + b8 + 4);
        uint4 o;
        o.x = pack2h(a.x, a.y);
        o.y = pack2h(a.z, a.w);
        o.z = pack2h(b.x, b.y);
        o.w = pack2h(b.z, b.w);
        *(uint4*)(fbf + b8) = o;
    }
}

// ------ fused layer: fdot2 agg + K-SPLIT f16 GEMM ------
// agg: 16 waves, 1 node/wave, half-wave edge split. Batch 0 (slots 0..15, the whole
// loop for ~54% of nodes at mean deg=16) issues its record loads deg-INDEPENDENTLY
// (padded array always mapped) so they run parallel to the cursor load — garbage
// src clamped to row 0, garbage weights zeroed by the deg-predicate at VALU time.
// GEMM: mfma f16, all 16 waves, K-split; upper-half partials via LDS.
template <int DIN, bool OUTF16>
__global__ __launch_bounds__(1024, 8) void layer_fused(
    const ushort* __restrict__ hbf, const int* __restrict__ cursor,
    const uint* __restrict__ recs, int woff,
    const ushort* __restrict__ Bt, const float* __restrict__ bias,
    void* __restrict__ hout) {
    constexpr int KD = 4 * DIN;
    constexpr int PITCH = KD + 8;   // ushorts; 16B-aligned rows
    constexpr int B = 8;            // batch slots; 16 edges (2 per slot via halves)
    constexpr int FPL = DIN / 32;   // features per lane (2 or 4)
    __shared__ __align__(16) ushort Ts[16 * PITCH];
    __shared__ __align__(16) f32x4 red[8][64];  // K-split partials (8 KB)
    int wv = threadIdx.x >> 6, lane = threadIdx.x & 63;
    int l16 = lane & 15, quad = lane >> 4;
    int half = lane >> 5, l32 = lane & 31;
    int nb = blockIdx.x * 16;
    int n = nb + wv;

    // ---- aggregation: one node per wave, fdot2 accumulate ----
    {
        int deg = __builtin_amdgcn_readfirstlane(cursor[n]);
        deg = deg < SLOT ? deg : SLOT;  // safety clamp
        size_t base = (size_t)n * SLOT;

        float acc[4 * FPL];
#pragma unroll
        for (int j = 0; j < 4 * FPL; ++j) acc[j] = 0.f;

        // ---- batch 0: slots 0..15, loads issued without deg dependence ----
        {
            int s[B];
            uint wlo[B], whi[B];
            uint2 hv[B];
#pragma unroll
            for (int u = 0; u < B; ++u) {
                size_t idx = base + 2 * u + half;  // always in-bounds (padded array)
                const uint* r = recs + idx * 8;
                int sv = (int)r[0];
                uint2 wp = *(const uint2*)(r + woff);
                bool ok = (2 * u + half) < deg;    // masking at VALU time only
                s[u] = ok ? sv : 0;                // clamp garbage src -> row 0 (mapped)
                wlo[u] = ok ? wp.x : 0u;
                whi[u] = ok ? wp.y : 0u;
            }
#pragma unroll
            for (int u = 0; u < B; ++u) {
                const ushort* rowp = hbf + (size_t)s[u] * DIN + l32 * FPL;
                if (DIN == 64)
                    hv[u].x = *(const uint*)rowp;
                else
                    hv[u] = *(const uint2*)rowp;
            }
#pragma unroll
            for (int u = 0; u < B; u += 2) {
                uint wp0 = pack_lo(wlo[u], wlo[u + 1]);
                uint wp1 = pack_hi(wlo[u], wlo[u + 1]);
                uint wp2 = pack_lo(whi[u], whi[u + 1]);
                uint wp3 = pack_hi(whi[u], whi[u + 1]);
                h16x2 w2[4] = {u2h2(wp0), u2h2(wp1), u2h2(wp2), u2h2(wp3)};
                h16x2 f2[FPL];
                f2[0] = u2h2(pack_lo(hv[u].x, hv[u + 1].x));
                f2[1] = u2h2(pack_hi(hv[u].x, hv[u + 1].x));
                if (DIN == 128) {
                    f2[2] = u2h2(pack_lo(hv[u].y, hv[u + 1].y));
                    f2[3] = u2h2(pack_hi(hv[u].y, hv[u + 1].y));
                }
#pragma unroll
                for (int k = 0; k < 4; ++k)
#pragma unroll
                    for (int j = 0; j < FPL; ++j)
                        acc[k * FPL + j] = __builtin_amdgcn_fdot2(
                            w2[k], f2[j], acc[k * FPL + j], false);
            }
        }
        // ---- remaining batches (deg > 16) ----
        for (int i = 16; i < deg; i += 2 * B) {
            int s[B];
            uint wlo[B], whi[B];
            uint2 hv[B];
#pragma unroll
            for (int u = 0; u < B; ++u) {
                int ii = i + 2 * u + half;
                bool ok = ii < deg;
                size_t idx = base + (ok ? ii : 0);
                const uint* r = recs + idx * 8;
                s[u] = (int)r[0];
                uint2 wp = *(const uint2*)(r + woff);
                wlo[u] = ok ? wp.x : 0u;
                whi[u] = ok ? wp.y : 0u;
            }
#pragma unroll
            for (int u = 0; u < B; ++u) {
                const ushort* rowp = hbf + (size_t)s[u] * DIN + l32 * FPL;
                if (DIN == 64)
                    hv[u].x = *(const uint*)rowp;
                else
                    hv[u] = *(const uint2*)rowp;
            }
#pragma unroll
            for (int u = 0; u < B; u += 2) {
                uint wp0 = pack_lo(wlo[u], wlo[u + 1]);
                uint wp1 = pack_hi(wlo[u], wlo[u + 1]);
                uint wp2 = pack_lo(whi[u], whi[u + 1]);
                uint wp3 = pack_hi(whi[u], whi[u + 1]);
                h16x2 w2[4] = {u2h2(wp0), u2h2(wp1), u2h2(wp2), u2h2(wp3)};
                h16x2 f2[FPL];
                f2[0] = u2h2(pack_lo(hv[u].x, hv[u + 1].x));
                f2[1] = u2h2(pack_hi(hv[u].x, hv[u + 1].x));
                if (DIN == 128) {
                    f2[2] = u2h2(pack_lo(hv[u].y, hv[u + 1].y));
                    f2[3] = u2h2(pack_hi(hv[u].y, hv[u + 1].y));
                }
#pragma unroll
                for (int k = 0; k < 4; ++k)
#pragma unroll
                    for (int j = 0; j < FPL; ++j)
                        acc[k * FPL + j] = __builtin_amdgcn_fdot2(
                            w2[k], f2[j], acc[k * FPL + j], false);
            }
        }
        // cross-half combine
#pragma unroll
        for (int j = 0; j < 4 * FPL; ++j) acc[j] += __shfl_xor(acc[j], 32);

        if (half == 0) {
#pragma unroll
            for (int k = 0; k < 4; ++k) {
                if (DIN == 64) {
                    ushort2 p;
                    p.x = f2h(acc[k * 2 + 0]);
                    p.y = f2h(acc[k * 2 + 1]);
                    *(ushort2*)(Ts + wv * PITCH + k * DIN + l32 * 2) = p;
                } else {
                    ushort4 p;
                    p.x = f2h(acc[k * 4 + 0]);
                    p.y = f2h(acc[k * 4 + 1]);
                    p.z = f2h(acc[k * 4 + 2]);
                    p.w = f2h(acc[k * 4 + 3]);
                    *(ushort4*)(Ts + wv * PITCH + k * DIN + l32 * 4) = p;
                }
            }
        }
    }
    __syncthreads();

    // ---- GEMM phase: 16 waves, K-split, f16 MFMA. wave wv -> col (wv&7)*16, K-half (wv>>3) ----
    {
        constexpr int KH = KD / 2;
        int kh = wv >> 3;
        int ct = wv & 7;
        int c0 = ct * 16;
        f32x4 accg = (f32x4){0.f, 0.f, 0.f, 0.f};
        int kbeg = kh * KH;
#pragma unroll 4
        for (int k0 = kbeg; k0 < kbeg + KH; k0 += 32) {
            f16x8 af = *(const f16x8*)(Ts + l16 * PITCH + k0 + quad * 8);
            f16x8 bfr = *(const f16x8*)(Bt + (size_t)(c0 + l16) * KD + k0 + quad * 8);
            accg = __builtin_amdgcn_mfma_f32_16x16x32_f16(af, bfr, accg, 0, 0, 0);
        }
        if (kh == 1) red[ct][lane] = accg;
        __syncthreads();
        if (kh == 0) {
            f32x4 other = red[ct][lane];
            int gn = c0 + l16;
            float bv = bias[gn];
#pragma unroll
            for (int i = 0; i < 4; ++i) {
                int gm = nb + quad * 4 + i;
                float val = accg[i] + other[i] + bv;
                if (OUTF16)
                    ((ushort*)hout)[(size_t)gm * 128 + gn] = f2h(val);
                else
                    ((float*)hout)[(size_t)gm * 128 + gn] = val;
            }
        }
    }
}

extern "C" void kernel_launch(void* const* d_in, const int* in_sizes, int n_in,
                              void* d_out, int out_size, void* d_ws, size_t ws_size,
                              hipStream_t stream) {
    const float* features = (const float*)d_in[0];
    const float* pseudo = (const float*)d_in[1];
    const int* src = (const int*)d_in[2];
    const int* dst = (const int*)d_in[3];
    const float* fc_w[3] = {(const float*)d_in[4], (const float*)d_in[10], (const float*)d_in[16]};
    const float* mu[3] = {(const float*)d_in[5], (const float*)d_in[11], (const float*)d_in[17]};
    const float* isg[3] = {(const float*)d_in[6], (const float*)d_in[12], (const float*)d_in[18]};
    const float* bias[3] = {(const float*)d_in[7], (const float*)d_in[13], (const float*)d_in[19]};
    const float* pw[3] = {(const float*)d_in[8], (const float*)d_in[14], (const float*)d_in[20]};
    const float* pb[3] = {(const float*)d_in[9], (const float*)d_in[15], (const float*)d_in[21]};

    char* ws = (char*)d_ws;
    auto alloc = [&](size_t bytes) -> void* {
        void* p = (void*)ws;
        ws += (bytes + 255) & ~(size_t)255;
        return p;
    };
    int* cursor = (int*)alloc((size_t)NN * 4);
    uint* recs = (uint*)alloc((size_t)NN * SLOT * 32);   // 32B record per slot
    ushort* fbf = (ushort*)alloc((size_t)NN * 64 * 2);   // features in f16
    ushort* w2t_0 = (ushort*)alloc((size_t)128 * 256 * 2);
    ushort* w2t_1 = (ushort*)alloc((size_t)128 * 512 * 2);
    ushort* w2t_2 = (ushort*)alloc((size_t)128 * 512 * 2);
    ushort* h1 = (ushort*)alloc((size_t)NN * 128 * 2);
    ushort* h2 = (ushort*)alloc((size_t)NN * 128 * 2);

    hipMemsetAsync(cursor, 0, (size_t)NN * 4, stream);
    EdgeParams P;
    P.pw0 = pw[0]; P.pb0 = pb[0]; P.mu0 = mu[0]; P.is0 = isg[0];
    P.pw1 = pw[1]; P.pb1 = pb[1]; P.mu1 = mu[1]; P.is1 = isg[1];
    P.pw2 = pw[2]; P.pb2 = pb[2]; P.mu2 = mu[2]; P.is2 = isg[2];
    fill_prep<<<1915, 256, 0, stream>>>(dst, src, pseudo, P, cursor, recs, features, fbf,
                                        fc_w[0], fc_w[1], fc_w[2], w2t_0, w2t_1, w2t_2);

    const int GB = NN / 16;  // 1250 blocks, 16 waves each, 1 node/wave

    layer_fused<64, true><<<GB, 1024, 0, stream>>>(
        fbf, cursor, recs, 2, w2t_0, bias[0], h1);
    layer_fused<128, true><<<GB, 1024, 0, stream>>>(
        h1, cursor, recs, 4, w2t_1, bias[1], h2);
    layer_fused<128, false><<<GB, 1024, 0, stream>>>(
        h2, cursor, recs, 6, w2t_2, bias[2], (float*)d_out);
}